// Round 1
// baseline (87.182 us; speedup 1.0000x reference)
//
#include <hip/hip_runtime.h>
#include <math.h>

#define NPT 320
#define DDIM 256
#define NN2 (NPT*NPT)          // 102400
#define MINN 1e-15f

// ---------------- init accumulators ----------------
__global__ void k_init(double* gsum, unsigned long long* gcnt) {
    *gsum = 0.0;
    *gcnt = 0ULL;
}

// ---------------- per-row reductions: x2, nn, pa ----------------
__global__ __launch_bounds__(256) void k_rows(const float* __restrict__ off,
                                              const float* __restrict__ nrm,
                                              float* __restrict__ x2,
                                              float* __restrict__ nn,
                                              float* __restrict__ pa) {
    int i = blockIdx.x;
    int t = threadIdx.x;
    float o = off[i * DDIM + t];
    float n = nrm[i * DDIM + t];
    float s0 = o * o, s1 = n * n, s2 = o * n;
    for (int d = 32; d; d >>= 1) {
        s0 += __shfl_down(s0, d);
        s1 += __shfl_down(s1, d);
        s2 += __shfl_down(s2, d);
    }
    __shared__ float r0[4], r1[4], r2[4];
    int w = t >> 6;
    if ((t & 63) == 0) { r0[w] = s0; r1[w] = s1; r2[w] = s2; }
    __syncthreads();
    if (t == 0) {
        x2[i] = r0[0] + r0[1] + r0[2] + r0[3];
        nn[i] = r1[0] + r1[1] + r1[2] + r1[3];
        pa[i] = r2[0] + r2[1] + r2[2] + r2[3];
    }
}

// ---------------- dm[i,j] 16x16 tile per block ----------------
__global__ __launch_bounds__(256) void k_dm(const float* __restrict__ off,
                                            const float* __restrict__ nrm,
                                            const float* __restrict__ curv,
                                            const float* __restrict__ x2,
                                            const float* __restrict__ nn,
                                            const float* __restrict__ pa,
                                            float* __restrict__ dm) {
    __shared__ float sOI[16][260];
    __shared__ float sOJ[16][260];
    __shared__ float sNJ[16][260];
    const float c = curv[0];
    const float sqrtc = sqrtf(c);
    const int I0 = blockIdx.y * 16, J0 = blockIdx.x * 16;
    const int t = threadIdx.x;
    const int r = t >> 4;
    const int cb = (t & 15) << 4;   // 16 floats per thread

    const float4* pOI = (const float4*)&off[(I0 + r) * DDIM + cb];
    const float4* pOJ = (const float4*)&off[(J0 + r) * DDIM + cb];
    const float4* pNJ = (const float4*)&nrm[(J0 + r) * DDIM + cb];
#pragma unroll
    for (int q = 0; q < 4; ++q) {
        *(float4*)&sOI[r][cb + 4 * q] = pOI[q];
        *(float4*)&sOJ[r][cb + 4 * q] = pOJ[q];
        *(float4*)&sNJ[r][cb + 4 * q] = pNJ[q];
    }
    __syncthreads();

    const int ti = t >> 4, tj = t & 15;
    float g = 0.f, h = 0.f;
#pragma unroll 8
    for (int d = 0; d < DDIM; ++d) {
        float oi = sOI[ti][d];
        g = fmaf(oi, sOJ[tj][d], g);
        h = fmaf(oi, sNJ[tj][d], h);
    }

    const int i = I0 + ti, j = J0 + tj;
    const float x2i = x2[i], x2j = x2[j], nnj = nn[j], paj = pa[j];
    const float cu = 1.f - 2.f * c * g + c * x2i;
    const float cv = 1.f - c * x2j;           // == conformal factor of row j
    float den0 = 1.f - 2.f * c * g + c * c * x2i * x2j;
    den0 = fmaxf(den0, MINN);
    float dn2 = (cu * cu * x2j - 2.f * cu * cv * g + cv * cv * x2i) / (den0 * den0);
    dn2 = fmaxf(dn2, MINN);
    const float sc = cv * (cv * h - cu * paj) / den0;
    const float an = fmaxf(fabsf(cv) * sqrtf(nnj), MINN);
    const float numv = 2.f * sqrtc * sc;
    const float denv = fmaxf((1.f - c * dn2) * an, MINN);
    const float z = numv / denv;
    const float dist = asinhf(z) / sqrtc;
    dm[i * NPT + j] = expf(dist);
}

// ---------------- triplet scan over N^3 mask ----------------
__global__ __launch_bounds__(256) void k_trip(const int* __restrict__ mask,
                                              const float* __restrict__ dm,
                                              double* __restrict__ gsum,
                                              unsigned long long* __restrict__ gcnt) {
    const int nI4 = (NPT * NPT * NPT) / 4;   // 8192000
    double s = 0.0;
    unsigned int cnt = 0;
    const int4* m4 = (const int4*)mask;
    const int stride = gridDim.x * blockDim.x;
    for (int f = blockIdx.x * blockDim.x + threadIdx.x; f < nI4; f += stride) {
        const int idx = f << 2;
        const int i = idx / NN2;
        const int rem = idx - i * NN2;
        const int j = rem / NPT;
        const int k = rem - j * NPT;
        const int4 m = m4[f];
        const float dij = dm[i * NPT + j];
        const float4 dk = *(const float4*)&dm[i * NPT + k];
        const float t0 = dk.x - dij, t1 = dk.y - dij, t2 = dk.z - dij, t3 = dk.w - dij;
        bool p0 = m.x && (t0 > 1e-16f);
        bool p1 = m.y && (t1 > 1e-16f);
        bool p2 = m.z && (t2 > 1e-16f);
        bool p3 = m.w && (t3 > 1e-16f);
        if (p0) { s += (double)t0; ++cnt; }
        if (p1) { s += (double)t1; ++cnt; }
        if (p2) { s += (double)t2; ++cnt; }
        if (p3) { s += (double)t3; ++cnt; }
    }
    // wave reduce (64 lanes)
    for (int o = 32; o; o >>= 1) {
        s += __shfl_down(s, o);
        cnt += __shfl_down(cnt, o);
    }
    __shared__ double ss[4];
    __shared__ unsigned int scn[4];
    const int w = threadIdx.x >> 6;
    if ((threadIdx.x & 63) == 0) { ss[w] = s; scn[w] = cnt; }
    __syncthreads();
    if (threadIdx.x == 0) {
        const double S = ss[0] + ss[1] + ss[2] + ss[3];
        const unsigned long long C =
            (unsigned long long)scn[0] + scn[1] + scn[2] + scn[3];
        atomicAdd(gsum, S);
        atomicAdd(gcnt, C);
    }
}

// ---------------- finalize ----------------
__global__ void k_fin(const double* __restrict__ gsum,
                      const unsigned long long* __restrict__ gcnt,
                      float* __restrict__ out) {
    unsigned long long c = *gcnt;
    if (c == 0ULL) c = 1ULL;
    out[0] = (float)(*gsum / (double)c);
}

extern "C" void kernel_launch(void* const* d_in, const int* in_sizes, int n_in,
                              void* d_out, int out_size, void* d_ws, size_t ws_size,
                              hipStream_t stream) {
    const float* off  = (const float*)d_in[0];
    const float* nrm  = (const float*)d_in[1];
    const float* curv = (const float*)d_in[2];
    const int*   mask = (const int*)d_in[3];
    float* out = (float*)d_out;

    char* ws = (char*)d_ws;
    double* gsum = (double*)ws;
    unsigned long long* gcnt = (unsigned long long*)(ws + 8);
    float* fws = (float*)(ws + 64);
    float* x2 = fws;
    float* nn = fws + NPT;
    float* pa = fws + 2 * NPT;
    float* dm = fws + 1024;        // 320*320 floats = 409600 B

    k_init<<<1, 1, 0, stream>>>(gsum, gcnt);
    k_rows<<<NPT, 256, 0, stream>>>(off, nrm, x2, nn, pa);
    k_dm<<<dim3(NPT / 16, NPT / 16), 256, 0, stream>>>(off, nrm, curv, x2, nn, pa, dm);
    k_trip<<<2048, 256, 0, stream>>>(mask, dm, gsum, gcnt);
    k_fin<<<1, 1, 0, stream>>>(gsum, gcnt, out);
}

// Round 2
// 72.312 us; speedup vs baseline: 1.2056x; 1.2056x over previous
//
#include <hip/hip_runtime.h>
#include <math.h>

#define NPT 320
#define DDIM 256
#define NN2 (NPT*NPT)          // 102400
#define MINN 1e-15f

#define CHUNKS 5
#define PLANE4 (NN2/4)         // 25600 int4 per plane
#define CHUNK4 (PLANE4/CHUNKS) // 5120 int4 per chunk
#define ITERS  (CHUNK4/256)    // 20 int4 per thread

// ---------------- init accumulators ----------------
__global__ void k_init(double* gsum, unsigned long long* gcnt) {
    *gsum = 0.0;
    *gcnt = 0ULL;
}

// ---------------- per-row reductions: x2, nn, pa ----------------
__global__ __launch_bounds__(256) void k_rows(const float* __restrict__ off,
                                              const float* __restrict__ nrm,
                                              float* __restrict__ x2,
                                              float* __restrict__ nn,
                                              float* __restrict__ pa) {
    int i = blockIdx.x;
    int t = threadIdx.x;
    float o = off[i * DDIM + t];
    float n = nrm[i * DDIM + t];
    float s0 = o * o, s1 = n * n, s2 = o * n;
    for (int d = 32; d; d >>= 1) {
        s0 += __shfl_down(s0, d);
        s1 += __shfl_down(s1, d);
        s2 += __shfl_down(s2, d);
    }
    __shared__ float r0[4], r1[4], r2[4];
    int w = t >> 6;
    if ((t & 63) == 0) { r0[w] = s0; r1[w] = s1; r2[w] = s2; }
    __syncthreads();
    if (t == 0) {
        x2[i] = r0[0] + r0[1] + r0[2] + r0[3];
        nn[i] = r1[0] + r1[1] + r1[2] + r1[3];
        pa[i] = r2[0] + r2[1] + r2[2] + r2[3];
    }
}

// ---------------- dm[i,j] 16x16 tile per block ----------------
__global__ __launch_bounds__(256) void k_dm(const float* __restrict__ off,
                                            const float* __restrict__ nrm,
                                            const float* __restrict__ curv,
                                            const float* __restrict__ x2,
                                            const float* __restrict__ nn,
                                            const float* __restrict__ pa,
                                            float* __restrict__ dm) {
    __shared__ float sOI[16][260];
    __shared__ float sOJ[16][260];
    __shared__ float sNJ[16][260];
    const float c = curv[0];
    const float sqrtc = sqrtf(c);
    const int I0 = blockIdx.y * 16, J0 = blockIdx.x * 16;
    const int t = threadIdx.x;
    const int r = t >> 4;
    const int cb = (t & 15) << 4;   // 16 floats per thread

    const float4* pOI = (const float4*)&off[(I0 + r) * DDIM + cb];
    const float4* pOJ = (const float4*)&off[(J0 + r) * DDIM + cb];
    const float4* pNJ = (const float4*)&nrm[(J0 + r) * DDIM + cb];
#pragma unroll
    for (int q = 0; q < 4; ++q) {
        *(float4*)&sOI[r][cb + 4 * q] = pOI[q];
        *(float4*)&sOJ[r][cb + 4 * q] = pOJ[q];
        *(float4*)&sNJ[r][cb + 4 * q] = pNJ[q];
    }
    __syncthreads();

    const int ti = t >> 4, tj = t & 15;
    float g = 0.f, h = 0.f;
#pragma unroll 8
    for (int d = 0; d < DDIM; ++d) {
        float oi = sOI[ti][d];
        g = fmaf(oi, sOJ[tj][d], g);
        h = fmaf(oi, sNJ[tj][d], h);
    }

    const int i = I0 + ti, j = J0 + tj;
    const float x2i = x2[i], x2j = x2[j], nnj = nn[j], paj = pa[j];
    const float cu = 1.f - 2.f * c * g + c * x2i;
    const float cv = 1.f - c * x2j;
    float den0 = 1.f - 2.f * c * g + c * c * x2i * x2j;
    den0 = fmaxf(den0, MINN);
    float dn2 = (cu * cu * x2j - 2.f * cu * cv * g + cv * cv * x2i) / (den0 * den0);
    dn2 = fmaxf(dn2, MINN);
    const float sc = cv * (cv * h - cu * paj) / den0;
    const float an = fmaxf(fabsf(cv) * sqrtf(nnj), MINN);
    const float numv = 2.f * sqrtc * sc;
    const float denv = fmaxf((1.f - c * dn2) * an, MINN);
    const float z = numv / denv;
    const float dist = asinhf(z) / sqrtc;
    dm[i * NPT + j] = expf(dist);
}

// ---------------- triplet scan: one plane-chunk per block ----------------
__global__ __launch_bounds__(256) void k_trip(const int* __restrict__ mask,
                                              const float* __restrict__ dm,
                                              double* __restrict__ gsum,
                                              unsigned long long* __restrict__ gcnt) {
    __shared__ __align__(16) float dmrow[NPT];
    const int bx = blockIdx.x;
    const int i = bx / CHUNKS;
    const int chunk = bx - i * CHUNKS;
    const int t = threadIdx.x;

    for (int v = t; v < NPT; v += 256) dmrow[v] = dm[i * NPT + v];
    __syncthreads();

    const int4* m4 = (const int4*)mask + (size_t)i * PLANE4 + (size_t)chunk * CHUNK4;
    const float4* dm4 = (const float4*)dmrow;

    float s = 0.f;
    unsigned cnt = 0;

#define PROC(B, U) { \
        const unsigned lin = (unsigned)(chunk * CHUNK4 + t + 256 * (U)); \
        const unsigned jj = lin / 80u; \
        const unsigned k4 = lin - jj * 80u; \
        const float dij = dmrow[jj]; \
        const float4 dk = dm4[k4]; \
        const float t0 = dk.x - dij, t1 = dk.y - dij, t2 = dk.z - dij, t3 = dk.w - dij; \
        const bool p0 = (B).x && (t0 > 1e-16f); \
        const bool p1 = (B).y && (t1 > 1e-16f); \
        const bool p2 = (B).z && (t2 > 1e-16f); \
        const bool p3 = (B).w && (t3 > 1e-16f); \
        s += p0 ? t0 : 0.f; cnt += p0; \
        s += p1 ? t1 : 0.f; cnt += p1; \
        s += p2 ? t2 : 0.f; cnt += p2; \
        s += p3 ? t3 : 0.f; cnt += p3; }

#pragma unroll 1
    for (int g = 0; g < ITERS / 4; ++g) {
        const int u0 = g * 4;
        // 4 independent 16B loads in flight before any consume
        const int4 b0 = m4[t + 256 * (u0 + 0)];
        const int4 b1 = m4[t + 256 * (u0 + 1)];
        const int4 b2 = m4[t + 256 * (u0 + 2)];
        const int4 b3 = m4[t + 256 * (u0 + 3)];
        PROC(b0, u0 + 0)
        PROC(b1, u0 + 1)
        PROC(b2, u0 + 2)
        PROC(b3, u0 + 3)
    }
#undef PROC

    // wave reduce (64 lanes), f64 from here on
    double sd = (double)s;
    for (int o = 32; o; o >>= 1) {
        sd += __shfl_down(sd, o);
        cnt += __shfl_down(cnt, o);
    }
    __shared__ double ss[4];
    __shared__ unsigned scn[4];
    const int w = t >> 6;
    if ((t & 63) == 0) { ss[w] = sd; scn[w] = cnt; }
    __syncthreads();
    if (t == 0) {
        atomicAdd(gsum, ss[0] + ss[1] + ss[2] + ss[3]);
        atomicAdd(gcnt, (unsigned long long)(scn[0] + scn[1] + scn[2] + scn[3]));
    }
}

// ---------------- finalize ----------------
__global__ void k_fin(const double* __restrict__ gsum,
                      const unsigned long long* __restrict__ gcnt,
                      float* __restrict__ out) {
    unsigned long long c = *gcnt;
    if (c == 0ULL) c = 1ULL;
    out[0] = (float)(*gsum / (double)c);
}

extern "C" void kernel_launch(void* const* d_in, const int* in_sizes, int n_in,
                              void* d_out, int out_size, void* d_ws, size_t ws_size,
                              hipStream_t stream) {
    const float* off  = (const float*)d_in[0];
    const float* nrm  = (const float*)d_in[1];
    const float* curv = (const float*)d_in[2];
    const int*   mask = (const int*)d_in[3];
    float* out = (float*)d_out;

    char* ws = (char*)d_ws;
    double* gsum = (double*)ws;
    unsigned long long* gcnt = (unsigned long long*)(ws + 8);
    float* fws = (float*)(ws + 64);
    float* x2 = fws;
    float* nn = fws + NPT;
    float* pa = fws + 2 * NPT;
    float* dm = fws + 1024;        // 320*320 floats = 409600 B

    k_init<<<1, 1, 0, stream>>>(gsum, gcnt);
    k_rows<<<NPT, 256, 0, stream>>>(off, nrm, x2, nn, pa);
    k_dm<<<dim3(NPT / 16, NPT / 16), 256, 0, stream>>>(off, nrm, curv, x2, nn, pa, dm);
    k_trip<<<NPT * CHUNKS, 256, 0, stream>>>(mask, dm, gsum, gcnt);
    k_fin<<<1, 1, 0, stream>>>(gsum, gcnt, out);
}